// Round 4
// baseline (1956.014 us; speedup 1.0000x reference)
//
#include <hip/hip_runtime.h>
#include <hip/hip_bf16.h>

#define Nb 256
#define Tt 512
#define Dd 64
#define TD (Tt * Dd)

__device__ __forceinline__ float sigmoidf_(float x) { return 1.0f / (1.0f + __expf(-x)); }
__device__ __forceinline__ float tanhf_(float x) {
    x = fminf(fmaxf(x, -15.0f), 15.0f);
    float e = __expf(2.0f * x);
    return (e - 1.0f) / (e + 1.0f);
}
// Barrier that drains ONLY LDS (cross-wave data is LDS-only here).
// Global stores + prefetch loads stay in flight — no vmcnt(0) drain.
__device__ __forceinline__ void bar_lds() {
    asm volatile("s_waitcnt lgkmcnt(0)\n\ts_barrier" ::: "memory");
}

// One block per batch row. 4 waves.
// Registers: W_lstm column (128) + U_lstm column (64) per thread = 192 VGPR (fits in 256).
// LDS: per-wave specialized matrices (W_hist/W_gh/W_feat/W_beta), float4-packed along k
//      (measured 0 bank conflicts with this layout in round 2).
// z-columns: wave w owns all 4 gates of h-elements j in [16w,16w+16)
// -> LSTM cell update is in-wave via shuffles (no extra barrier).
__global__ __launch_bounds__(256, 1) void rits_kernel(
    const float* __restrict__ inp,
    const float* __restrict__ W_hist, const float* __restrict__ b_hist,
    const float* __restrict__ W_feat, const float* __restrict__ b_feat,
    const float* __restrict__ W_gx,   const float* __restrict__ b_gx,
    const float* __restrict__ W_gh,   const float* __restrict__ b_gh,
    const float* __restrict__ W_beta, const float* __restrict__ b_beta,
    const float* __restrict__ W_lstm, const float* __restrict__ U_lstm,
    const float* __restrict__ b_lstm,
    const float* __restrict__ W_out,  const float* __restrict__ b_out,
    float* __restrict__ out)
{
    __shared__ __align__(16) float4 s_wh[1024];   // W_hist  16 KB
    __shared__ __align__(16) float4 s_wg[1024];   // W_gh    16 KB
    __shared__ __align__(16) float4 s_wf[1024];   // W_feat  16 KB (diag zeroed)
    __shared__ __align__(16) float4 s_wb[2048];   // W_beta  32 KB
    __shared__ __align__(16) float s_h[64];
    __shared__ __align__(16) float s_d[64];
    __shared__ __align__(16) float s_m[64];
    __shared__ __align__(16) float s_x[64];
    __shared__ __align__(16) float s_cat[128];
    __shared__ __align__(16) float s_xhat[64];
    __shared__ __align__(16) float s_xc[64];
    __shared__ __align__(16) float s_hp[64];
    __shared__ __align__(16) float s_bt[64];
    __shared__ __align__(16) float s_cc[64];

    const int tid  = threadIdx.x;
    const int wave = tid >> 6;
    const int j    = tid & 63;
    const int jl   = j & 15;
    const int gate = j >> 4;
    const int n    = blockIdx.x;

    // ---- stage specialized weights into LDS (float4 packed along k) ----
    for (int idx = tid; idx < 1024; idx += 256) {
        int k4 = idx >> 6, jj = idx & 63;
        int k0 = 4 * k4;
        s_wh[idx] = make_float4(W_hist[(k0 + 0) * 64 + jj], W_hist[(k0 + 1) * 64 + jj],
                                W_hist[(k0 + 2) * 64 + jj], W_hist[(k0 + 3) * 64 + jj]);
        s_wg[idx] = make_float4(W_gh[(k0 + 0) * 64 + jj], W_gh[(k0 + 1) * 64 + jj],
                                W_gh[(k0 + 2) * 64 + jj], W_gh[(k0 + 3) * 64 + jj]);
        s_wf[idx] = make_float4((k0 + 0 == jj) ? 0.0f : W_feat[(k0 + 0) * 64 + jj],
                                (k0 + 1 == jj) ? 0.0f : W_feat[(k0 + 1) * 64 + jj],
                                (k0 + 2 == jj) ? 0.0f : W_feat[(k0 + 2) * 64 + jj],
                                (k0 + 3 == jj) ? 0.0f : W_feat[(k0 + 3) * 64 + jj]);
    }
    for (int idx = tid; idx < 2048; idx += 256) {
        int k4 = idx >> 6, jj = idx & 63;
        int k0 = 4 * k4;
        s_wb[idx] = make_float4(W_beta[(k0 + 0) * 64 + jj], W_beta[(k0 + 1) * 64 + jj],
                                W_beta[(k0 + 2) * 64 + jj], W_beta[(k0 + 3) * 64 + jj]);
    }

    // z column owned by this thread: gate*64 + 16*wave + jl
    const int col = (gate << 6) + (wave << 4) + jl;

    // ---- register-resident z-matmul weights (192 VGPR) ----
    float wl[128], wu[64];
#pragma unroll
    for (int k = 0; k < 128; ++k) wl[k] = W_lstm[k * 256 + col];
#pragma unroll
    for (int k = 0; k < 64; ++k)  wu[k] = U_lstm[k * 256 + col];
    const float bl = b_lstm[col];

    // per-wave LDS weight base
    const float4* Wlds = (wave == 0) ? s_wh : (wave == 1) ? s_wg
                       : (wave == 2) ? s_wf : s_wb;
    const float bwv = (wave == 0) ? b_hist[j] : (wave == 1) ? b_gh[j]
                    : (wave == 2) ? b_feat[j] : b_beta[j];

    float gxw = 0, gxb = 0, wout = 0, bo = 0;
    if (wave == 0) {
        gxw = W_gx[j * 64 + j]; gxb = b_gx[j];
        wout = W_out[j]; bo = b_out[0];
    }

    const size_t base = (size_t)n * (3 * TD);
    float nx = 0, nm = 0, nd = 0;
    float c = 0.0f;

    if (wave == 0) {
        float x0 = inp[base + j], m0 = inp[base + TD + j], d0 = inp[base + 2 * TD + j];
        s_x[j] = x0; s_m[j] = m0; s_d[j] = d0;
        s_cat[j] = __expf(-fmaxf(fmaf(d0, gxw, gxb), 0.0f));
        s_cat[64 + j] = m0;
        nx = inp[base + Dd + j];
        nm = inp[base + TD + Dd + j];
        nd = inp[base + 2 * TD + Dd + j];
    } else if (wave == 1) {
        s_h[j] = 0.0f;
    }
    bar_lds();

#pragma unroll 1
    for (int t = 0; t < Tt; ++t) {
        float z0 = 0, z1 = 0, z2 = 0, z3 = 0;

        // ==== Stage A: x_hat | gamma_h | beta ; waves 0-2: m-part of z ====
        if (wave != 3) {
            const float4* m4 = reinterpret_cast<const float4*>(s_m);
#pragma unroll
            for (int k4 = 0; k4 < 16; ++k4) {
                float4 v = m4[k4];
                z0 = fmaf(v.x, wl[64 + 4 * k4 + 0], z0);
                z1 = fmaf(v.y, wl[64 + 4 * k4 + 1], z1);
                z2 = fmaf(v.z, wl[64 + 4 * k4 + 2], z2);
                z3 = fmaf(v.w, wl[64 + 4 * k4 + 3], z3);
            }
        }
        if (wave == 0) {
            float a0 = 0, a1 = 0, a2 = 0, a3 = 0;
            const float4* h4 = reinterpret_cast<const float4*>(s_h);
#pragma unroll
            for (int k4 = 0; k4 < 16; ++k4) {
                float4 w = Wlds[(k4 << 6) + j];
                float4 v = h4[k4];
                a0 = fmaf(v.x, w.x, a0); a1 = fmaf(v.y, w.y, a1);
                a2 = fmaf(v.z, w.z, a2); a3 = fmaf(v.w, w.w, a3);
            }
            float acc = bwv + ((a0 + a1) + (a2 + a3));
            s_xhat[j] = acc;
            float xr = s_x[j], mr = s_m[j];
            s_xc[j] = fmaf(mr, xr, (1.0f - mr) * acc);
            out[(size_t)((n * 3 + 0) * Tt + t) * Dd + j] = acc;
        } else if (wave == 1) {
            float a0 = 0, a1 = 0, a2 = 0, a3 = 0;
            const float4* d4 = reinterpret_cast<const float4*>(s_d);
#pragma unroll
            for (int k4 = 0; k4 < 16; ++k4) {
                float4 w = Wlds[(k4 << 6) + j];
                float4 v = d4[k4];
                a0 = fmaf(v.x, w.x, a0); a1 = fmaf(v.y, w.y, a1);
                a2 = fmaf(v.z, w.z, a2); a3 = fmaf(v.w, w.w, a3);
            }
            float acc = bwv + ((a0 + a1) + (a2 + a3));
            float gh = __expf(-fmaxf(acc, 0.0f));
            s_hp[j] = s_h[j] * gh;
        } else if (wave == 3) {
            float a0 = 0, a1 = 0, a2 = 0, a3 = 0;
            const float4* c4 = reinterpret_cast<const float4*>(s_cat);
#pragma unroll
            for (int k4 = 0; k4 < 32; ++k4) {
                float4 w = Wlds[(k4 << 6) + j];
                float4 v = c4[k4];
                a0 = fmaf(v.x, w.x, a0); a1 = fmaf(v.y, w.y, a1);
                a2 = fmaf(v.z, w.z, a2); a3 = fmaf(v.w, w.w, a3);
            }
            s_bt[j] = sigmoidf_(bwv + ((a0 + a1) + (a2 + a3)));
        }
        bar_lds();

        // ==== Stage B: all: U-part of z ; wave2: z_hat->c_hat->cc ; wave3: m-part ====
        {
            const float4* h4 = reinterpret_cast<const float4*>(s_hp);
#pragma unroll
            for (int k4 = 0; k4 < 16; ++k4) {
                float4 v = h4[k4];
                z0 = fmaf(v.x, wu[4 * k4 + 0], z0);
                z1 = fmaf(v.y, wu[4 * k4 + 1], z1);
                z2 = fmaf(v.z, wu[4 * k4 + 2], z2);
                z3 = fmaf(v.w, wu[4 * k4 + 3], z3);
            }
        }
        if (wave == 3) {
            const float4* m4 = reinterpret_cast<const float4*>(s_m);
#pragma unroll
            for (int k4 = 0; k4 < 16; ++k4) {
                float4 v = m4[k4];
                z0 = fmaf(v.x, wl[64 + 4 * k4 + 0], z0);
                z1 = fmaf(v.y, wl[64 + 4 * k4 + 1], z1);
                z2 = fmaf(v.z, wl[64 + 4 * k4 + 2], z2);
                z3 = fmaf(v.w, wl[64 + 4 * k4 + 3], z3);
            }
        } else if (wave == 2) {
            float a0 = 0, a1 = 0, a2 = 0, a3 = 0;
            const float4* x4 = reinterpret_cast<const float4*>(s_xc);
#pragma unroll
            for (int k4 = 0; k4 < 16; ++k4) {
                float4 w = Wlds[(k4 << 6) + j];
                float4 v = x4[k4];
                a0 = fmaf(v.x, w.x, a0); a1 = fmaf(v.y, w.y, a1);
                a2 = fmaf(v.z, w.z, a2); a3 = fmaf(v.w, w.w, a3);
            }
            float acc = bwv + ((a0 + a1) + (a2 + a3));
            float bt = s_bt[j];
            float chat = bt * acc + (1.0f - bt) * s_xhat[j];
            float mj = s_m[j], xj = s_x[j];
            s_cc[j] = fmaf(mj, xj, (1.0f - mj) * chat);
            out[(size_t)((n * 3 + 1) * Tt + t) * Dd + j] = acc;
            out[(size_t)((n * 3 + 2) * Tt + t) * Dd + j] = chat;
        }
        bar_lds();

        // ==== Stage C: all: cc-part of z ; in-wave LSTM update ; wave0: stage t+1 ====
        {
            const float4* c4 = reinterpret_cast<const float4*>(s_cc);
#pragma unroll
            for (int k4 = 0; k4 < 16; ++k4) {
                float4 v = c4[k4];
                z0 = fmaf(v.x, wl[4 * k4 + 0], z0);
                z1 = fmaf(v.y, wl[4 * k4 + 1], z1);
                z2 = fmaf(v.z, wl[4 * k4 + 2], z2);
                z3 = fmaf(v.w, wl[4 * k4 + 3], z3);
            }
        }
        float z = bl + ((z0 + z1) + (z2 + z3));
        float zi = __shfl(z, jl, 64);
        float zf = __shfl(z, 16 + jl, 64);
        float zg = __shfl(z, 32 + jl, 64);
        float zo = __shfl(z, 48 + jl, 64);
        c = sigmoidf_(zf) * c + sigmoidf_(zi) * tanhf_(zg);
        float hn = sigmoidf_(zo) * tanhf_(c);
        if (gate == 0) s_h[(wave << 4) + jl] = hn;

        if (wave == 0 && t + 1 < Tt) {
            s_x[j] = nx; s_m[j] = nm; s_d[j] = nd;
            s_cat[j] = __expf(-fmaxf(fmaf(nd, gxw, gxb), 0.0f));
            s_cat[64 + j] = nm;
            if (t + 2 < Tt) {
                nx = inp[base + (t + 2) * Dd + j];
                nm = inp[base + TD + (t + 2) * Dd + j];
                nd = inp[base + 2 * TD + (t + 2) * Dd + j];
            }
        }
        bar_lds();
    }

    // final prediction: sigmoid(h_last @ W_out + b_out)
    if (wave == 0) {
        float p = s_h[j] * wout;
#pragma unroll
        for (int off = 32; off > 0; off >>= 1) p += __shfl_down(p, off, 64);
        if (j == 0) out[(size_t)Nb * 3 * TD + n] = sigmoidf_(p + bo);
    }
}

extern "C" void kernel_launch(void* const* d_in, const int* in_sizes, int n_in,
                              void* d_out, int out_size, void* d_ws, size_t ws_size,
                              hipStream_t stream) {
    (void)in_sizes; (void)n_in; (void)out_size; (void)d_ws; (void)ws_size;
    const float* inp    = (const float*)d_in[0];
    const float* W_hist = (const float*)d_in[1];
    const float* b_hist = (const float*)d_in[2];
    const float* W_feat = (const float*)d_in[3];
    const float* b_feat = (const float*)d_in[4];
    const float* W_gx   = (const float*)d_in[5];
    const float* b_gx   = (const float*)d_in[6];
    const float* W_gh   = (const float*)d_in[7];
    const float* b_gh   = (const float*)d_in[8];
    const float* W_beta = (const float*)d_in[9];
    const float* b_beta = (const float*)d_in[10];
    const float* W_lstm = (const float*)d_in[11];
    const float* U_lstm = (const float*)d_in[12];
    const float* b_lstm = (const float*)d_in[13];
    const float* W_out  = (const float*)d_in[14];
    const float* b_out  = (const float*)d_in[15];
    float* out = (float*)d_out;

    rits_kernel<<<dim3(Nb), dim3(256), 0, stream>>>(
        inp, W_hist, b_hist, W_feat, b_feat, W_gx, b_gx, W_gh, b_gh,
        W_beta, b_beta, W_lstm, U_lstm, b_lstm, W_out, b_out, out);
}